// Round 9
// baseline (242.634 us; speedup 1.0000x reference)
//
#include <hip/hip_runtime.h>

typedef __bf16 bf16_t;
typedef __attribute__((ext_vector_type(8))) __bf16 bf16x8;
typedef __attribute__((ext_vector_type(4))) float f32x4;

#define IMG_H 56
#define IMG_W 56
#define CIN 256
#define COUT 256
#define TH 8        // output rows per block
#define TW 16       // output cols per block
#define XR 10       // halo rows
#define XCOL 18     // halo cols
#define CK 32       // c-chunk
#define PH 58       // padded H (1-px zero border)
#define PW 58       // padded W
#define NPIX (XR * XCOL)            // 180 pixels per halo tile
#define NUNIT (NPIX * 5)            // 900 16B-units (5th = pad, skipped)
#define NISSUE ((NUNIT + 63) / 64)  // 15 wave-issues
#define XS_ELEMS (NPIX * 40)        // 7200 bf16 per buffer (80B/pixel)

#define XBF_BYTES ((size_t)32 * PH * PW * CIN * 2)   // 55,115,776
#define WT_BYTES  ((size_t)9 * COUT * CIN * 2)       // 1,179,648

// ---- weight permute: W[k][c][3][3] fp32 -> wt2 in MFMA fragment order ------
// elem offset = t*65536 + ch*8192 + half*4096 + fn*512 + lane*8 + j
// maps to W[k][c] tap t with k=half*128+fn*16+(lane&15), c=ch*32+(lane>>4)*8+j
__global__ void wt_permute(const float* __restrict__ W, bf16_t* __restrict__ wt2) {
    int u = blockIdx.x * 256 + threadIdx.x;   // 73728 groups
    int lane = u & 63;
    int fn   = (u >> 6) & 7;
    int half = (u >> 9) & 1;
    int ch   = (u >> 10) & 7;
    int t    = u >> 13;
    int g = lane >> 4, pc = lane & 15;
    int k  = half * 128 + fn * 16 + pc;
    int cb = ch * 32 + g * 8;
    bf16x8 v;
    #pragma unroll
    for (int j = 0; j < 8; ++j)
        v[j] = (bf16_t)W[(k * CIN + cb + j) * 9 + t];
    *(bf16x8*)(wt2 + (size_t)u * 8) = v;
}

// ---- x transpose: x[n][c][h][w] fp32 -> xbf[n][ph][pw][c] bf16, borders=0 ---
#define LSP 258   // LDS row stride (elems)
__global__ __launch_bounds__(256)
void x_to_bf16(const float* __restrict__ x, bf16_t* __restrict__ xbf) {
    __shared__ bf16_t ls[IMG_W * LSP];
    const int n = blockIdx.y, ph = blockIdx.x;   // ph: 0..57 padded row
    bf16_t* drow = xbf + (size_t)(n * PH + ph) * PW * CIN;
    const f32x4 zf = {0.f, 0.f, 0.f, 0.f};
    if (ph == 0 || ph == PH - 1) {
        for (int i = threadIdx.x; i < PW * CIN / 8; i += 256)
            ((f32x4*)drow)[i] = zf;          // zero whole padded row
        return;
    }
    // zero left (w=0) and right (w=57) border pixels
    for (int i = threadIdx.x; i < 2 * CIN / 8; i += 256) {
        int side = i >> 5, off = i & 31;
        ((f32x4*)(drow + (side ? (size_t)(PW - 1) * CIN : 0)))[off] = zf;
    }
    const int h = ph - 1;
    const float* src = x + ((size_t)n * CIN * IMG_H + h) * IMG_W;
    for (int e = threadIdx.x; e < CIN * IMG_W; e += 256) {
        int c = e / IMG_W, w = e - c * IMG_W;
        ls[w * LSP + c] = (bf16_t)src[(size_t)c * (IMG_H * IMG_W) + w];
    }
    __syncthreads();
    bf16_t* dst = drow + CIN;    // w=1 (first interior col)
    for (int i = threadIdx.x; i < IMG_W * (CIN / 8); i += 256) {
        int w = i >> 5, cp = (i & 31) * 8;
        bf16x8 v;
        #pragma unroll
        for (int j = 0; j < 8; ++j) v[j] = ls[w * LSP + cp + j];
        *(bf16x8*)(dst + (size_t)w * CIN + cp) = v;
    }
}

// ---- main conv: implicit GEMM; wave = 64 px x 64 k (FM=4, FN=4);
//      rotating B prefetch (cross-chunk), 4 blocks/CU -----------------------
__global__ __launch_bounds__(256, 4)
void conv_mfma(const bf16_t* __restrict__ xbf, const bf16_t* __restrict__ wt2,
               float* __restrict__ out) {
    __shared__ __align__(16) bf16_t xs[2][XS_ELEMS];   // 2 x 14400 B

    const int tid  = threadIdx.x;
    const int lane = tid & 63;
    const int wid  = tid >> 6;      // 0..3
    const int n    = blockIdx.z >> 1;
    const int bk   = blockIdx.z & 1;    // k-half of this block
    const int h0   = blockIdx.y * TH;
    const int w0   = blockIdx.x * TW;

    const int wm   = wid >> 1;      // px half
    const int kq2  = wid & 1;       // k quarter-within-half
    const int pc   = lane & 15;
    const int g    = lane >> 4;

    f32x4 acc[4][4] = {};           // 64 px x 64 k per wave
    // B fragment base: k = bk*128 + kq2*64 + q*16 + pc  (half=bk, fn=kq2*4+q)
    const bf16_t* wfrag = wt2 + (size_t)lane * 8 + (size_t)bk * 4096
                              + (size_t)kq2 * 2048;
    const bf16_t* xn = xbf + (size_t)n * (PH * PW * CIN);

    // staging descriptors as 32-bit element offsets (-1 = inactive slot)
    int soff[4];
    #pragma unroll
    for (int s = 0; s < 4; ++s) {
        int j = wid + s * 4;
        int u = j * 64 + lane;
        int p = u / 5, q = u - p * 5;
        bool ok = (j < NISSUE) && (u < NUNIT) && (q < 4);
        int r = p / XCOL, col = p - r * XCOL;
        int w = w0 + col; if (w > PW - 1) w = PW - 1;   // clamp into zero border
        int rr = (r > XR - 1) ? (XR - 1) : r;
        soff[s] = ok ? (((h0 + rr) * PW + w) * CIN + q * 8) : -1;
    }

    auto STAGE = [&](int buf, int ch) {
        #pragma unroll
        for (int s = 0; s < 4; ++s)
            if (soff[s] >= 0)
                __builtin_amdgcn_global_load_lds(
                    (const __attribute__((address_space(1))) void*)(xn + soff[s] + ch * CK),
                    (__attribute__((address_space(3))) void*)(&xs[buf][(wid + s * 4) * 512]),
                    16, 0, 0);
    };

    // prologue: B tap-0 of chunk 0 + stage chunk 0
    bf16x8 bcur[4];
    #pragma unroll
    for (int q = 0; q < 4; ++q)
        bcur[q] = *(const bf16x8*)(wfrag + q * 512);
    STAGE(0, 0);
    __syncthreads();   // buf0 ready; bcur loads drained too

    for (int ch = 0; ch < 8; ++ch) {
        const int cur = ch & 1;
        const bf16_t* wch = wfrag + (size_t)ch * 8192;

        if (ch < 7) STAGE(cur ^ 1, ch + 1);   // async prefetch next chunk

        // tap order: dw outer, dh inner (t = dh*3+dw); A rows loaded once per dw.
        // B prefetch rotates in place: q=2,3 computed -> reload; q=0,1 -> reload.
        // Last tap of a chunk prefetches the NEXT chunk's tap 0 (+8192 elems).
        #pragma unroll
        for (int dw = 0; dw < 3; ++dw) {
            bf16x8 a[6];
            #pragma unroll
            for (int r = 0; r < 6; ++r)
                a[r] = *(const bf16x8*)&xs[cur][((wm * 4 + r) * XCOL + pc + dw) * 40 + g * 8];
            #pragma unroll
            for (int dh = 0; dh < 3; ++dh) {
                const bool lastTap = (dw == 2) && (dh == 2);
                const int tn = (dh < 2) ? ((dh + 1) * 3 + dw) : (dw + 1);
                const bf16_t* wp = lastTap ? (wch + 8192)
                                           : (wch + (size_t)tn * 65536);
                const bool doPf = !(lastTap && ch == 7);
                #pragma unroll
                for (int fm = 0; fm < 4; ++fm) {
                    acc[fm][2] = __builtin_amdgcn_mfma_f32_16x16x32_bf16(
                        a[fm + dh], bcur[2], acc[fm][2], 0, 0, 0);
                    acc[fm][3] = __builtin_amdgcn_mfma_f32_16x16x32_bf16(
                        a[fm + dh], bcur[3], acc[fm][3], 0, 0, 0);
                }
                if (doPf) {
                    bcur[2] = *(const bf16x8*)(wp + 1024);
                    bcur[3] = *(const bf16x8*)(wp + 1536);
                }
                #pragma unroll
                for (int fm = 0; fm < 4; ++fm) {
                    acc[fm][0] = __builtin_amdgcn_mfma_f32_16x16x32_bf16(
                        a[fm + dh], bcur[0], acc[fm][0], 0, 0, 0);
                    acc[fm][1] = __builtin_amdgcn_mfma_f32_16x16x32_bf16(
                        a[fm + dh], bcur[1], acc[fm][1], 0, 0, 0);
                }
                if (doPf) {
                    bcur[0] = *(const bf16x8*)(wp);
                    bcur[1] = *(const bf16x8*)(wp + 512);
                }
            }
        }
        __syncthreads();   // xs[cur] free; next buffer + next B0 drained
    }

    // epilogue: C/D col=lane&15 (within-16 k), row=g*4+reg (w offset)
    const int wcol = w0 + g * 4;
    if (wcol < IMG_W) {
        #pragma unroll
        for (int fm = 0; fm < 4; ++fm) {
            int hh = h0 + wm * 4 + fm;
            #pragma unroll
            for (int q = 0; q < 4; ++q) {
                int k = bk * 128 + kq2 * 64 + q * 16 + pc;
                *(f32x4*)&out[((n * COUT + k) * IMG_H + hh) * IMG_W + wcol] = acc[fm][q];
            }
        }
    }
}

// ---- mid fallback: B direct global, scalar x staging (round-2 proven) -------
#define CPAD 40
__global__ __launch_bounds__(256, 2)
void conv_mfma_v2(const float* __restrict__ x, const bf16_t* __restrict__ wt2,
                  float* __restrict__ out) {
    __shared__ bf16_t xsl[XR * XCOL * CPAD];
    const int tid  = threadIdx.x;
    const int lane = tid & 63;
    const int wid  = tid >> 6;
    const int n    = blockIdx.z;
    const int h0   = blockIdx.y * TH;
    const int w0   = blockIdx.x * TW;
    const int wm   = wid >> 1;
    const int half = wid & 1;
    const int pc = lane & 15;
    const int g  = lane >> 4;
    const int c0 = g * 8;
    f32x4 acc[4][8] = {};
    const bf16_t* wch_base = wt2 + (size_t)lane * 8 + (size_t)half * 4096;
    for (int ch = 0; ch < 8; ++ch) {
        __syncthreads();
        for (int e = tid; e < XR * XCOL * CK; e += 256) {
            int col = e % XCOL;
            int r   = (e / XCOL) % XR;
            int ci  = e / (XCOL * XR);
            int hh = h0 - 1 + r;
            int ww = w0 - 1 + col;
            float v = 0.f;
            if ((unsigned)hh < (unsigned)IMG_H && (unsigned)ww < (unsigned)IMG_W)
                v = x[((n * CIN + ch * CK + ci) * IMG_H + hh) * IMG_W + ww];
            xsl[(r * XCOL + col) * CPAD + ci] = (bf16_t)v;
        }
        __syncthreads();
        const bf16_t* wch = wch_base + (size_t)ch * 8192;
        #pragma unroll 3
        for (int t = 0; t < 9; ++t) {
            const int dh = t / 3, dw = t % 3;
            const bf16_t* wp = wch + (size_t)t * 65536;
            bf16x8 b[8];
            #pragma unroll
            for (int fn = 0; fn < 8; ++fn)
                b[fn] = *(const bf16x8*)(wp + fn * 512);
            bf16x8 a[4];
            #pragma unroll
            for (int fm = 0; fm < 4; ++fm)
                a[fm] = *(const bf16x8*)&xsl[((wm * 4 + fm + dh) * XCOL + (pc + dw)) * CPAD + c0];
            #pragma unroll
            for (int fm = 0; fm < 4; ++fm)
                #pragma unroll
                for (int fn = 0; fn < 8; ++fn)
                    acc[fm][fn] = __builtin_amdgcn_mfma_f32_16x16x32_bf16(
                        a[fm], b[fn], acc[fm][fn], 0, 0, 0);
        }
    }
    const int wcol = w0 + g * 4;
    if (wcol < IMG_W) {
        #pragma unroll
        for (int fm = 0; fm < 4; ++fm) {
            int hh = h0 + wm * 4 + fm;
            #pragma unroll
            for (int fn = 0; fn < 8; ++fn) {
                int k = half * 128 + fn * 16 + pc;
                *(f32x4*)&out[((n * COUT + k) * IMG_H + hh) * IMG_W + wcol] = acc[fm][fn];
            }
        }
    }
}

// ---- last-resort fallback: naive fp32 conv ----------------------------------
__global__ void conv_naive(const float* __restrict__ x, const float* __restrict__ W,
                           float* __restrict__ out, int total) {
    int i = blockIdx.x * 256 + threadIdx.x;
    if (i >= total) return;
    int w = i % IMG_W;
    int h = (i / IMG_W) % IMG_H;
    int k = (i / (IMG_W * IMG_H)) % COUT;
    int n = i / (IMG_W * IMG_H * COUT);
    float s = 0.f;
    for (int c = 0; c < CIN; ++c) {
        #pragma unroll
        for (int dh = 0; dh < 3; ++dh) {
            int hh = h + dh - 1;
            if ((unsigned)hh >= (unsigned)IMG_H) continue;
            #pragma unroll
            for (int dw = 0; dw < 3; ++dw) {
                int ww = w + dw - 1;
                if ((unsigned)ww >= (unsigned)IMG_W) continue;
                s += x[((n * CIN + c) * IMG_H + hh) * IMG_W + ww] *
                     W[((k * CIN + c) * 3 + dh) * 3 + dw];
            }
        }
    }
    out[i] = s;
}

extern "C" void kernel_launch(void* const* d_in, const int* in_sizes, int n_in,
                              void* d_out, int out_size, void* d_ws, size_t ws_size,
                              hipStream_t stream) {
    const float* x = (const float*)d_in[0];
    const float* W = (const float*)d_in[1];
    float* out = (float*)d_out;

    if (ws_size >= XBF_BYTES + WT_BYTES) {
        bf16_t* xbf = (bf16_t*)d_ws;
        bf16_t* wt2 = (bf16_t*)((char*)d_ws + XBF_BYTES);
        wt_permute<<<dim3(288), dim3(256), 0, stream>>>(W, wt2);
        x_to_bf16<<<dim3(PH, 32), dim3(256), 0, stream>>>(x, xbf);   // writes borders
        conv_mfma<<<dim3(4, 7, 64), dim3(256), 0, stream>>>(xbf, wt2, out);
    } else if (ws_size >= WT_BYTES) {
        bf16_t* wt2 = (bf16_t*)d_ws;
        wt_permute<<<dim3(288), dim3(256), 0, stream>>>(W, wt2);
        conv_mfma_v2<<<dim3(4, 7, 32), dim3(256), 0, stream>>>(x, wt2, out);
    } else {
        int total = 32 * COUT * IMG_H * IMG_W;
        conv_naive<<<dim3((total + 255) / 256), dim3(256), 0, stream>>>(x, W, out, total);
    }
}

// Round 10
// 153.146 us; speedup vs baseline: 1.5843x; 1.5843x over previous
//
#include <hip/hip_runtime.h>

typedef __bf16 bf16_t;
typedef __attribute__((ext_vector_type(8))) __bf16 bf16x8;
typedef __attribute__((ext_vector_type(4))) float f32x4;

#define IMG_H 56
#define IMG_W 56
#define CIN 256
#define COUT 256
#define TH 8        // output rows per block
#define TW 16       // output cols per block
#define XR 10       // halo rows
#define XCOL 18     // halo cols
#define CK 32       // c-chunk
#define PH 58       // padded H (1-px zero border)
#define PW 58       // padded W
#define NPIX (XR * XCOL)            // 180 pixels per halo tile
#define NUNIT (NPIX * 5)            // 900 16B-units (5th = pad, skipped)
#define NISSUE ((NUNIT + 63) / 64)  // 15 wave-issues
#define XS_ELEMS (NPIX * 40)        // 7200 bf16 per buffer (80B/pixel)

#define NBLK 1792                   // 4 * 7 * 64
#define CPX  (NBLK / 8)             // 224 blocks per XCD chunk

#define XBF_BYTES ((size_t)32 * PH * PW * CIN * 2)   // 55,115,776
#define WT_BYTES  ((size_t)9 * COUT * CIN * 2)       // 1,179,648

// ---- weight permute: W[k][c][3][3] fp32 -> wt2 in MFMA fragment order ------
// elem offset = t*65536 + ch*8192 + half*4096 + fn*512 + lane*8 + j
// maps to W[k][c] tap t with k=half*128+fn*16+(lane&15), c=ch*32+(lane>>4)*8+j
__global__ void wt_permute(const float* __restrict__ W, bf16_t* __restrict__ wt2) {
    int u = blockIdx.x * 256 + threadIdx.x;   // 73728 groups
    int lane = u & 63;
    int fn   = (u >> 6) & 7;
    int half = (u >> 9) & 1;
    int ch   = (u >> 10) & 7;
    int t    = u >> 13;
    int g = lane >> 4, pc = lane & 15;
    int k  = half * 128 + fn * 16 + pc;
    int cb = ch * 32 + g * 8;
    bf16x8 v;
    #pragma unroll
    for (int j = 0; j < 8; ++j)
        v[j] = (bf16_t)W[(k * CIN + cb + j) * 9 + t];
    *(bf16x8*)(wt2 + (size_t)u * 8) = v;
}

// ---- x transpose: x[n][c][h][w] fp32 -> xbf[n][ph][pw][c] bf16, borders=0 ---
#define LSP 258   // LDS row stride (elems)
__global__ __launch_bounds__(256)
void x_to_bf16(const float* __restrict__ x, bf16_t* __restrict__ xbf) {
    __shared__ bf16_t ls[IMG_W * LSP];
    const int n = blockIdx.y, ph = blockIdx.x;   // ph: 0..57 padded row
    bf16_t* drow = xbf + (size_t)(n * PH + ph) * PW * CIN;
    const f32x4 zf = {0.f, 0.f, 0.f, 0.f};
    if (ph == 0 || ph == PH - 1) {
        for (int i = threadIdx.x; i < PW * CIN / 8; i += 256)
            ((f32x4*)drow)[i] = zf;          // zero whole padded row
        return;
    }
    // zero left (w=0) and right (w=57) border pixels
    for (int i = threadIdx.x; i < 2 * CIN / 8; i += 256) {
        int side = i >> 5, off = i & 31;
        ((f32x4*)(drow + (side ? (size_t)(PW - 1) * CIN : 0)))[off] = zf;
    }
    const int h = ph - 1;
    const float* src = x + ((size_t)n * CIN * IMG_H + h) * IMG_W;
    for (int e = threadIdx.x; e < CIN * IMG_W; e += 256) {
        int c = e / IMG_W, w = e - c * IMG_W;
        ls[w * LSP + c] = (bf16_t)src[(size_t)c * (IMG_H * IMG_W) + w];
    }
    __syncthreads();
    bf16_t* dst = drow + CIN;    // w=1 (first interior col)
    for (int i = threadIdx.x; i < IMG_W * (CIN / 8); i += 256) {
        int w = i >> 5, cp = (i & 31) * 8;
        bf16x8 v;
        #pragma unroll
        for (int j = 0; j < 8; ++j) v[j] = ls[w * LSP + cp + j];
        *(bf16x8*)(dst + (size_t)w * CIN + cp) = v;
    }
}

// ---- main conv: implicit GEMM; wave = 64 px x 64 k (FM=4, FN=4);
//      full-tap B reg-dbuf + cross-chunk B0 prefetch; XCD-chunked swizzle ----
__global__ __launch_bounds__(256, 3)
void conv_mfma(const bf16_t* __restrict__ xbf, const bf16_t* __restrict__ wt2,
               float* __restrict__ out) {
    __shared__ __align__(16) bf16_t xs[2][XS_ELEMS];   // 2 x 14400 B

    const int tid  = threadIdx.x;
    const int lane = tid & 63;
    const int wid  = tid >> 6;      // 0..3

    // XCD-chunked bijective swizzle: hw%8 = XCD -> contiguous logical chunk.
    // logical layout (bk innermost): bk + 2*(wx + 4*(hy + 7*n))
    const int hw      = blockIdx.x;
    const int logical = (hw & 7) * CPX + (hw >> 3);
    const int bk = logical & 1;         // k-half of this block
    int tmp = logical >> 1;
    const int wx = tmp & 3;  tmp >>= 2;
    const int hy = tmp % 7;
    const int n  = tmp / 7;
    const int h0 = hy * TH;
    const int w0 = wx * TW;

    const int wm   = wid >> 1;      // px half
    const int kq2  = wid & 1;       // k quarter-within-half
    const int pc   = lane & 15;
    const int g    = lane >> 4;

    f32x4 acc[4][4] = {};           // 64 px x 64 k per wave
    // B fragment base: k = bk*128 + kq2*64 + q*16 + pc  (half=bk, fn=kq2*4+q)
    const bf16_t* wfrag = wt2 + (size_t)lane * 8 + (size_t)bk * 4096
                              + (size_t)kq2 * 2048;
    const bf16_t* xn = xbf + (size_t)n * (PH * PW * CIN);

    // staging descriptors as 32-bit element offsets (-1 = inactive slot)
    int soff[4];
    #pragma unroll
    for (int s = 0; s < 4; ++s) {
        int j = wid + s * 4;
        int u = j * 64 + lane;
        int p = u / 5, q = u - p * 5;
        bool ok = (j < NISSUE) && (u < NUNIT) && (q < 4);
        int r = p / XCOL, col = p - r * XCOL;
        int w = w0 + col; if (w > PW - 1) w = PW - 1;   // clamp into zero border
        int rr = (r > XR - 1) ? (XR - 1) : r;
        soff[s] = ok ? (((h0 + rr) * PW + w) * CIN + q * 8) : -1;
    }

    auto STAGE = [&](int buf, int ch) {
        #pragma unroll
        for (int s = 0; s < 4; ++s)
            if (soff[s] >= 0)
                __builtin_amdgcn_global_load_lds(
                    (const __attribute__((address_space(1))) void*)(xn + soff[s] + ch * CK),
                    (__attribute__((address_space(3))) void*)(&xs[buf][(wid + s * 4) * 512]),
                    16, 0, 0);
    };

    // prologue: B tap-0 of chunk 0 + stage chunk 0
    bf16x8 bcur[4], bnext[4];
    #pragma unroll
    for (int q = 0; q < 4; ++q)
        bcur[q] = *(const bf16x8*)(wfrag + q * 512);
    STAGE(0, 0);
    __syncthreads();   // buf0 ready; bcur drained too

    for (int ch = 0; ch < 8; ++ch) {
        const int cur = ch & 1;
        const bf16_t* wch = wfrag + (size_t)ch * 8192;

        if (ch < 7) STAGE(cur ^ 1, ch + 1);   // async prefetch next chunk

        // tap order: dw outer, dh inner (t = dh*3+dw); A rows loaded once per dw.
        // bnext prefetches one full tap ahead; last tap prefetches NEXT chunk's
        // tap 0 (+8192 elems) -> no B0 bubble after the barrier.
        #pragma unroll
        for (int dw = 0; dw < 3; ++dw) {
            bf16x8 a[6];
            #pragma unroll
            for (int r = 0; r < 6; ++r)
                a[r] = *(const bf16x8*)&xs[cur][((wm * 4 + r) * XCOL + pc + dw) * 40 + g * 8];
            #pragma unroll
            for (int dh = 0; dh < 3; ++dh) {
                const bool lastTap = (dw == 2) && (dh == 2);
                const bool doPf = !(lastTap && ch == 7);
                if (doPf) {
                    const int tn = (dh < 2) ? ((dh + 1) * 3 + dw) : (dw + 1);
                    const bf16_t* wp = lastTap ? (wch + 8192)
                                               : (wch + (size_t)tn * 65536);
                    #pragma unroll
                    for (int q = 0; q < 4; ++q)
                        bnext[q] = *(const bf16x8*)(wp + q * 512);
                }
                #pragma unroll
                for (int fm = 0; fm < 4; ++fm)
                    #pragma unroll
                    for (int q = 0; q < 4; ++q)
                        acc[fm][q] = __builtin_amdgcn_mfma_f32_16x16x32_bf16(
                            a[fm + dh], bcur[q], acc[fm][q], 0, 0, 0);
                if (doPf) {
                    #pragma unroll
                    for (int q = 0; q < 4; ++q) bcur[q] = bnext[q];  // SSA rename
                }
            }
        }
        __syncthreads();   // xs[cur] free; next buffer + next B0 drained
    }

    // epilogue: C/D col=lane&15 (within-16 k), row=g*4+reg (w offset)
    const int wcol = w0 + g * 4;
    if (wcol < IMG_W) {
        #pragma unroll
        for (int fm = 0; fm < 4; ++fm) {
            int hh = h0 + wm * 4 + fm;
            #pragma unroll
            for (int q = 0; q < 4; ++q) {
                int k = bk * 128 + kq2 * 64 + q * 16 + pc;
                *(f32x4*)&out[((n * COUT + k) * IMG_H + hh) * IMG_W + wcol] = acc[fm][q];
            }
        }
    }
}

// ---- mid fallback: B direct global, scalar x staging (round-2 proven) -------
#define CPAD 40
__global__ __launch_bounds__(256, 2)
void conv_mfma_v2(const float* __restrict__ x, const bf16_t* __restrict__ wt2,
                  float* __restrict__ out) {
    __shared__ bf16_t xsl[XR * XCOL * CPAD];
    const int tid  = threadIdx.x;
    const int lane = tid & 63;
    const int wid  = tid >> 6;
    const int n    = blockIdx.z;
    const int h0   = blockIdx.y * TH;
    const int w0   = blockIdx.x * TW;
    const int wm   = wid >> 1;
    const int half = wid & 1;
    const int pc = lane & 15;
    const int g  = lane >> 4;
    const int c0 = g * 8;
    f32x4 acc[4][8] = {};
    const bf16_t* wch_base = wt2 + (size_t)lane * 8 + (size_t)half * 4096;
    for (int ch = 0; ch < 8; ++ch) {
        __syncthreads();
        for (int e = tid; e < XR * XCOL * CK; e += 256) {
            int col = e % XCOL;
            int r   = (e / XCOL) % XR;
            int ci  = e / (XCOL * XR);
            int hh = h0 - 1 + r;
            int ww = w0 - 1 + col;
            float v = 0.f;
            if ((unsigned)hh < (unsigned)IMG_H && (unsigned)ww < (unsigned)IMG_W)
                v = x[((n * CIN + ch * CK + ci) * IMG_H + hh) * IMG_W + ww];
            xsl[(r * XCOL + col) * CPAD + ci] = (bf16_t)v;
        }
        __syncthreads();
        const bf16_t* wch = wch_base + (size_t)ch * 8192;
        #pragma unroll 3
        for (int t = 0; t < 9; ++t) {
            const int dh = t / 3, dw = t % 3;
            const bf16_t* wp = wch + (size_t)t * 65536;
            bf16x8 b[8];
            #pragma unroll
            for (int fn = 0; fn < 8; ++fn)
                b[fn] = *(const bf16x8*)(wp + fn * 512);
            bf16x8 a[4];
            #pragma unroll
            for (int fm = 0; fm < 4; ++fm)
                a[fm] = *(const bf16x8*)&xsl[((wm * 4 + fm + dh) * XCOL + (pc + dw)) * CPAD + c0];
            #pragma unroll
            for (int fm = 0; fm < 4; ++fm)
                #pragma unroll
                for (int fn = 0; fn < 8; ++fn)
                    acc[fm][fn] = __builtin_amdgcn_mfma_f32_16x16x32_bf16(
                        a[fm], b[fn], acc[fm][fn], 0, 0, 0);
        }
    }
    const int wcol = w0 + g * 4;
    if (wcol < IMG_W) {
        #pragma unroll
        for (int fm = 0; fm < 4; ++fm) {
            int hh = h0 + wm * 4 + fm;
            #pragma unroll
            for (int fn = 0; fn < 8; ++fn) {
                int k = half * 128 + fn * 16 + pc;
                *(f32x4*)&out[((n * COUT + k) * IMG_H + hh) * IMG_W + wcol] = acc[fm][fn];
            }
        }
    }
}

// ---- last-resort fallback: naive fp32 conv ----------------------------------
__global__ void conv_naive(const float* __restrict__ x, const float* __restrict__ W,
                           float* __restrict__ out, int total) {
    int i = blockIdx.x * 256 + threadIdx.x;
    if (i >= total) return;
    int w = i % IMG_W;
    int h = (i / IMG_W) % IMG_H;
    int k = (i / (IMG_W * IMG_H)) % COUT;
    int n = i / (IMG_W * IMG_H * COUT);
    float s = 0.f;
    for (int c = 0; c < CIN; ++c) {
        #pragma unroll
        for (int dh = 0; dh < 3; ++dh) {
            int hh = h + dh - 1;
            if ((unsigned)hh >= (unsigned)IMG_H) continue;
            #pragma unroll
            for (int dw = 0; dw < 3; ++dw) {
                int ww = w + dw - 1;
                if ((unsigned)ww >= (unsigned)IMG_W) continue;
                s += x[((n * CIN + c) * IMG_H + hh) * IMG_W + ww] *
                     W[((k * CIN + c) * 3 + dh) * 3 + dw];
            }
        }
    }
    out[i] = s;
}

extern "C" void kernel_launch(void* const* d_in, const int* in_sizes, int n_in,
                              void* d_out, int out_size, void* d_ws, size_t ws_size,
                              hipStream_t stream) {
    const float* x = (const float*)d_in[0];
    const float* W = (const float*)d_in[1];
    float* out = (float*)d_out;

    if (ws_size >= XBF_BYTES + WT_BYTES) {
        bf16_t* xbf = (bf16_t*)d_ws;
        bf16_t* wt2 = (bf16_t*)((char*)d_ws + XBF_BYTES);
        wt_permute<<<dim3(288), dim3(256), 0, stream>>>(W, wt2);
        x_to_bf16<<<dim3(PH, 32), dim3(256), 0, stream>>>(x, xbf);   // writes borders
        conv_mfma<<<dim3(NBLK), dim3(256), 0, stream>>>(xbf, wt2, out);
    } else if (ws_size >= WT_BYTES) {
        bf16_t* wt2 = (bf16_t*)d_ws;
        wt_permute<<<dim3(288), dim3(256), 0, stream>>>(W, wt2);
        conv_mfma_v2<<<dim3(4, 7, 32), dim3(256), 0, stream>>>(x, wt2, out);
    } else {
        int total = 32 * COUT * IMG_H * IMG_W;
        conv_naive<<<dim3((total + 255) / 256), dim3(256), 0, stream>>>(x, W, out, total);
    }
}

// Round 11
// 144.587 us; speedup vs baseline: 1.6781x; 1.0592x over previous
//
#include <hip/hip_runtime.h>

typedef __bf16 bf16_t;
typedef __attribute__((ext_vector_type(8))) __bf16 bf16x8;
typedef __attribute__((ext_vector_type(4))) float f32x4;

#define IMG_H 56
#define IMG_W 56
#define CIN 256
#define COUT 256
#define TH 8        // output rows per block
#define TW 16       // output cols per block
#define XR 10       // halo rows
#define XCOL 18     // halo cols
#define CK 32       // c-chunk
#define PH 58       // padded H (1-px zero border)
#define PW 58       // padded W
#define NPIX (XR * XCOL)            // 180 pixels per halo tile
#define NUNIT (NPIX * 5)            // 900 16B-units (5th = pad, skipped)
#define NISSUE ((NUNIT + 63) / 64)  // 15 wave-issues
#define XS_ELEMS (NPIX * 40)        // 7200 bf16 per buffer (80B/pixel)

#define NBLK 1792                   // 4 * 7 * 64
#define CPX  (NBLK / 8)             // 224 blocks per XCD chunk

#define XBF_BYTES ((size_t)32 * PH * PW * CIN * 2)   // 55,115,776
#define WT_BYTES  ((size_t)9 * COUT * CIN * 2)       // 1,179,648

// ---- weight permute: W[k][c][3][3] fp32 -> wt2 in MFMA fragment order ------
// elem offset = t*65536 + ch*8192 + half*4096 + fn*512 + lane*8 + j
// maps to W[k][c] tap t with k=half*128+fn*16+(lane&15), c=ch*32+(lane>>4)*8+j
__global__ void wt_permute(const float* __restrict__ W, bf16_t* __restrict__ wt2) {
    int u = blockIdx.x * 256 + threadIdx.x;   // 73728 groups
    int lane = u & 63;
    int fn   = (u >> 6) & 7;
    int half = (u >> 9) & 1;
    int ch   = (u >> 10) & 7;
    int t    = u >> 13;
    int g = lane >> 4, pc = lane & 15;
    int k  = half * 128 + fn * 16 + pc;
    int cb = ch * 32 + g * 8;
    bf16x8 v;
    #pragma unroll
    for (int j = 0; j < 8; ++j)
        v[j] = (bf16_t)W[(k * CIN + cb + j) * 9 + t];
    *(bf16x8*)(wt2 + (size_t)u * 8) = v;
}

// ---- x transpose: x[n][c][h][w] fp32 -> xbf[n][ph][pw][c] bf16, borders=0 ---
#define LSP 258   // LDS row stride (elems)
__global__ __launch_bounds__(256)
void x_to_bf16(const float* __restrict__ x, bf16_t* __restrict__ xbf) {
    __shared__ bf16_t ls[IMG_W * LSP];
    const int n = blockIdx.y, ph = blockIdx.x;   // ph: 0..57 padded row
    bf16_t* drow = xbf + (size_t)(n * PH + ph) * PW * CIN;
    const f32x4 zf = {0.f, 0.f, 0.f, 0.f};
    if (ph == 0 || ph == PH - 1) {
        for (int i = threadIdx.x; i < PW * CIN / 8; i += 256)
            ((f32x4*)drow)[i] = zf;          // zero whole padded row
        return;
    }
    // zero left (w=0) and right (w=57) border pixels
    for (int i = threadIdx.x; i < 2 * CIN / 8; i += 256) {
        int side = i >> 5, off = i & 31;
        ((f32x4*)(drow + (side ? (size_t)(PW - 1) * CIN : 0)))[off] = zf;
    }
    const int h = ph - 1;
    const float* src = x + ((size_t)n * CIN * IMG_H + h) * IMG_W;
    for (int e = threadIdx.x; e < CIN * IMG_W; e += 256) {
        int c = e / IMG_W, w = e - c * IMG_W;
        ls[w * LSP + c] = (bf16_t)src[(size_t)c * (IMG_H * IMG_W) + w];
    }
    __syncthreads();
    bf16_t* dst = drow + CIN;    // w=1 (first interior col)
    for (int i = threadIdx.x; i < IMG_W * (CIN / 8); i += 256) {
        int w = i >> 5, cp = (i & 31) * 8;
        bf16x8 v;
        #pragma unroll
        for (int j = 0; j < 8; ++j) v[j] = ls[w * LSP + cp + j];
        *(bf16x8*)(dst + (size_t)w * CIN + cp) = v;
    }
}

// ---- main conv: implicit GEMM; wave = 64 px x 64 k (FM=4, FN=4);
//      full-tap B reg-dbuf + cross-chunk B0 prefetch; XCD-chunked swizzle;
//      STAGE issued mid-tap-1 so B vmcnt-waits never force it early ---------
__global__ __launch_bounds__(256, 3)
void conv_mfma(const bf16_t* __restrict__ xbf, const bf16_t* __restrict__ wt2,
               float* __restrict__ out) {
    __shared__ __align__(16) bf16_t xs[2][XS_ELEMS];   // 2 x 14400 B

    const int tid  = threadIdx.x;
    const int lane = tid & 63;
    const int wid  = tid >> 6;      // 0..3

    // XCD-chunked bijective swizzle: hw%8 = XCD -> contiguous logical chunk.
    // logical layout (bk innermost): bk + 2*(wx + 4*(hy + 7*n))
    const int hw      = blockIdx.x;
    const int logical = (hw & 7) * CPX + (hw >> 3);
    const int bk = logical & 1;         // k-half of this block
    int tmp = logical >> 1;
    const int wx = tmp & 3;  tmp >>= 2;
    const int hy = tmp % 7;
    const int n  = tmp / 7;
    const int h0 = hy * TH;
    const int w0 = wx * TW;

    const int wm   = wid >> 1;      // px half
    const int kq2  = wid & 1;       // k quarter-within-half
    const int pc   = lane & 15;
    const int g    = lane >> 4;

    f32x4 acc[4][4] = {};           // 64 px x 64 k per wave
    // B fragment base: k = bk*128 + kq2*64 + q*16 + pc  (half=bk, fn=kq2*4+q)
    const bf16_t* wfrag = wt2 + (size_t)lane * 8 + (size_t)bk * 4096
                              + (size_t)kq2 * 2048;
    const bf16_t* xn = xbf + (size_t)n * (PH * PW * CIN);

    // staging descriptors as 32-bit element offsets (-1 = inactive slot)
    int soff[4];
    #pragma unroll
    for (int s = 0; s < 4; ++s) {
        int j = wid + s * 4;
        int u = j * 64 + lane;
        int p = u / 5, q = u - p * 5;
        bool ok = (j < NISSUE) && (u < NUNIT) && (q < 4);
        int r = p / XCOL, col = p - r * XCOL;
        int w = w0 + col; if (w > PW - 1) w = PW - 1;   // clamp into zero border
        int rr = (r > XR - 1) ? (XR - 1) : r;
        soff[s] = ok ? (((h0 + rr) * PW + w) * CIN + q * 8) : -1;
    }

    auto STAGE = [&](int buf, int ch) {
        #pragma unroll
        for (int s = 0; s < 4; ++s)
            if (soff[s] >= 0)
                __builtin_amdgcn_global_load_lds(
                    (const __attribute__((address_space(1))) void*)(xn + soff[s] + ch * CK),
                    (__attribute__((address_space(3))) void*)(&xs[buf][(wid + s * 4) * 512]),
                    16, 0, 0);
    };

    // prologue: B tap-0 of chunk 0 + stage chunk 0
    bf16x8 bcur[4], bnext[4];
    #pragma unroll
    for (int q = 0; q < 4; ++q)
        bcur[q] = *(const bf16x8*)(wfrag + q * 512);
    STAGE(0, 0);
    __syncthreads();   // buf0 ready; bcur drained too

    for (int ch = 0; ch < 8; ++ch) {
        const int cur = ch & 1;
        const bf16_t* wch = wfrag + (size_t)ch * 8192;

        // tap order: dw outer, dh inner (t = dh*3+dw); A rows loaded once per dw.
        // bnext prefetches one full tap ahead; last tap prefetches NEXT chunk's
        // tap 0 (+8192 elems) -> no B0 bubble after the barrier.
        // STAGE(next chunk) is issued between tap-1's bnext issue and tap-1's
        // MFMAs: B vmcnt-waits (in-order retirement) then only force STAGE
        // completion at tap (1,0), ~3 taps (~900 cyc) of cover.
        #pragma unroll
        for (int dw = 0; dw < 3; ++dw) {
            bf16x8 a[6];
            #pragma unroll
            for (int r = 0; r < 6; ++r)
                a[r] = *(const bf16x8*)&xs[cur][((wm * 4 + r) * XCOL + pc + dw) * 40 + g * 8];
            #pragma unroll
            for (int dh = 0; dh < 3; ++dh) {
                const bool lastTap = (dw == 2) && (dh == 2);
                const bool doPf = !(lastTap && ch == 7);
                if (doPf) {
                    const int tn = (dh < 2) ? ((dh + 1) * 3 + dw) : (dw + 1);
                    const bf16_t* wp = lastTap ? (wch + 8192)
                                               : (wch + (size_t)tn * 65536);
                    #pragma unroll
                    for (int q = 0; q < 4; ++q)
                        bnext[q] = *(const bf16x8*)(wp + q * 512);
                }
                if (dw == 0 && dh == 1 && ch < 7)
                    STAGE(cur ^ 1, ch + 1);   // async prefetch next chunk
                __builtin_amdgcn_s_setprio(1);
                #pragma unroll
                for (int fm = 0; fm < 4; ++fm)
                    #pragma unroll
                    for (int q = 0; q < 4; ++q)
                        acc[fm][q] = __builtin_amdgcn_mfma_f32_16x16x32_bf16(
                            a[fm + dh], bcur[q], acc[fm][q], 0, 0, 0);
                __builtin_amdgcn_s_setprio(0);
                if (doPf) {
                    #pragma unroll
                    for (int q = 0; q < 4; ++q) bcur[q] = bnext[q];  // SSA rename
                }
            }
        }
        __syncthreads();   // xs[cur] free; next buffer + next B0 drained
    }

    // epilogue: C/D col=lane&15 (within-16 k), row=g*4+reg (w offset)
    const int wcol = w0 + g * 4;
    if (wcol < IMG_W) {
        #pragma unroll
        for (int fm = 0; fm < 4; ++fm) {
            int hh = h0 + wm * 4 + fm;
            #pragma unroll
            for (int q = 0; q < 4; ++q) {
                int k = bk * 128 + kq2 * 64 + q * 16 + pc;
                *(f32x4*)&out[((n * COUT + k) * IMG_H + hh) * IMG_W + wcol] = acc[fm][q];
            }
        }
    }
}

// ---- mid fallback: B direct global, scalar x staging (round-2 proven) -------
#define CPAD 40
__global__ __launch_bounds__(256, 2)
void conv_mfma_v2(const float* __restrict__ x, const bf16_t* __restrict__ wt2,
                  float* __restrict__ out) {
    __shared__ bf16_t xsl[XR * XCOL * CPAD];
    const int tid  = threadIdx.x;
    const int lane = tid & 63;
    const int wid  = tid >> 6;
    const int n    = blockIdx.z;
    const int h0   = blockIdx.y * TH;
    const int w0   = blockIdx.x * TW;
    const int wm   = wid >> 1;
    const int half = wid & 1;
    const int pc = lane & 15;
    const int g  = lane >> 4;
    const int c0 = g * 8;
    f32x4 acc[4][8] = {};
    const bf16_t* wch_base = wt2 + (size_t)lane * 8 + (size_t)half * 4096;
    for (int ch = 0; ch < 8; ++ch) {
        __syncthreads();
        for (int e = tid; e < XR * XCOL * CK; e += 256) {
            int col = e % XCOL;
            int r   = (e / XCOL) % XR;
            int ci  = e / (XCOL * XR);
            int hh = h0 - 1 + r;
            int ww = w0 - 1 + col;
            float v = 0.f;
            if ((unsigned)hh < (unsigned)IMG_H && (unsigned)ww < (unsigned)IMG_W)
                v = x[((n * CIN + ch * CK + ci) * IMG_H + hh) * IMG_W + ww];
            xsl[(r * XCOL + col) * CPAD + ci] = (bf16_t)v;
        }
        __syncthreads();
        const bf16_t* wch = wch_base + (size_t)ch * 8192;
        #pragma unroll 3
        for (int t = 0; t < 9; ++t) {
            const int dh = t / 3, dw = t % 3;
            const bf16_t* wp = wch + (size_t)t * 65536;
            bf16x8 b[8];
            #pragma unroll
            for (int fn = 0; fn < 8; ++fn)
                b[fn] = *(const bf16x8*)(wp + fn * 512);
            bf16x8 a[4];
            #pragma unroll
            for (int fm = 0; fm < 4; ++fm)
                a[fm] = *(const bf16x8*)&xsl[((wm * 4 + fm + dh) * XCOL + (pc + dw)) * CPAD + c0];
            #pragma unroll
            for (int fm = 0; fm < 4; ++fm)
                #pragma unroll
                for (int fn = 0; fn < 8; ++fn)
                    acc[fm][fn] = __builtin_amdgcn_mfma_f32_16x16x32_bf16(
                        a[fm], b[fn], acc[fm][fn], 0, 0, 0);
        }
    }
    const int wcol = w0 + g * 4;
    if (wcol < IMG_W) {
        #pragma unroll
        for (int fm = 0; fm < 4; ++fm) {
            int hh = h0 + wm * 4 + fm;
            #pragma unroll
            for (int fn = 0; fn < 8; ++fn) {
                int k = half * 128 + fn * 16 + pc;
                *(f32x4*)&out[((n * COUT + k) * IMG_H + hh) * IMG_W + wcol] = acc[fm][fn];
            }
        }
    }
}

// ---- last-resort fallback: naive fp32 conv ----------------------------------
__global__ void conv_naive(const float* __restrict__ x, const float* __restrict__ W,
                           float* __restrict__ out, int total) {
    int i = blockIdx.x * 256 + threadIdx.x;
    if (i >= total) return;
    int w = i % IMG_W;
    int h = (i / IMG_W) % IMG_H;
    int k = (i / (IMG_W * IMG_H)) % COUT;
    int n = i / (IMG_W * IMG_H * COUT);
    float s = 0.f;
    for (int c = 0; c < CIN; ++c) {
        #pragma unroll
        for (int dh = 0; dh < 3; ++dh) {
            int hh = h + dh - 1;
            if ((unsigned)hh >= (unsigned)IMG_H) continue;
            #pragma unroll
            for (int dw = 0; dw < 3; ++dw) {
                int ww = w + dw - 1;
                if ((unsigned)ww >= (unsigned)IMG_W) continue;
                s += x[((n * CIN + c) * IMG_H + hh) * IMG_W + ww] *
                     W[((k * CIN + c) * 3 + dh) * 3 + dw];
            }
        }
    }
    out[i] = s;
}

extern "C" void kernel_launch(void* const* d_in, const int* in_sizes, int n_in,
                              void* d_out, int out_size, void* d_ws, size_t ws_size,
                              hipStream_t stream) {
    const float* x = (const float*)d_in[0];
    const float* W = (const float*)d_in[1];
    float* out = (float*)d_out;

    if (ws_size >= XBF_BYTES + WT_BYTES) {
        bf16_t* xbf = (bf16_t*)d_ws;
        bf16_t* wt2 = (bf16_t*)((char*)d_ws + XBF_BYTES);
        wt_permute<<<dim3(288), dim3(256), 0, stream>>>(W, wt2);
        x_to_bf16<<<dim3(PH, 32), dim3(256), 0, stream>>>(x, xbf);   // writes borders
        conv_mfma<<<dim3(NBLK), dim3(256), 0, stream>>>(xbf, wt2, out);
    } else if (ws_size >= WT_BYTES) {
        bf16_t* wt2 = (bf16_t*)d_ws;
        wt_permute<<<dim3(288), dim3(256), 0, stream>>>(W, wt2);
        conv_mfma_v2<<<dim3(4, 7, 32), dim3(256), 0, stream>>>(x, wt2, out);
    } else {
        int total = 32 * COUT * IMG_H * IMG_W;
        conv_naive<<<dim3((total + 255) / 256), dim3(256), 0, stream>>>(x, W, out, total);
    }
}